// Round 4
// baseline (1644.081 us; speedup 1.0000x reference)
//
#include <hip/hip_runtime.h>
#include <hip/hip_bf16.h>

#define NN 50000
#define NE 500000

__global__ void k_embed(const int* __restrict__ nt, const float* __restrict__ table,
                        float* __restrict__ nf){
  int i = blockIdx.x * 256 + threadIdx.x;
  if (i >= NN * 128) return;
  nf[i] = table[nt[i >> 7] * 128 + (i & 127)];
}

// ---------------- CSR build (once per launch; reused by both layers) ----------------
__global__ void k_zero2(int* __restrict__ cnt, int* __restrict__ cur){
  int i = blockIdx.x * 256 + threadIdx.x;
  if (i < NN){ cnt[i] = 0; cur[i] = 0; }
}

__global__ void k_hist(const int* __restrict__ dst, int* __restrict__ cnt){
  int e = blockIdx.x * 256 + threadIdx.x;
  if (e < NE) atomicAdd(&cnt[dst[e]], 1);
}

// single-block exclusive scan over NN counts -> off[0..NN]
__global__ __launch_bounds__(1024) void k_scan(const int* __restrict__ cnt,
                                               int* __restrict__ off){
  __shared__ int ws[16];
  __shared__ int blocktot;
  __shared__ int carry_s;
  int tid = threadIdx.x;
  int lane = tid & 63, wv = tid >> 6;
  if (tid == 0) carry_s = 0;
  for (int base = 0; base < NN; base += 1024){
    int i = base + tid;
    int v = (i < NN) ? cnt[i] : 0;
    int x = v;
    #pragma unroll
    for (int d = 1; d < 64; d <<= 1){
      int t = __shfl_up(x, d, 64);
      if (lane >= d) x += t;
    }
    if (lane == 63) ws[wv] = x;
    __syncthreads();                    // also orders carry_s init
    if (tid == 0){
      int a = 0;
      #pragma unroll
      for (int k2 = 0; k2 < 16; ++k2){ int t = ws[k2]; ws[k2] = a; a += t; }
      blocktot = a;
    }
    __syncthreads();
    int carry = carry_s;
    if (i < NN) off[i] = carry + ws[wv] + (x - v);   // exclusive
    __syncthreads();
    if (tid == 0) carry_s = carry + blocktot;
    __syncthreads();
  }
  if (tid == 0) off[NN] = carry_s;
}

// rank[e] = position of edge e in dst-grouped (CSR) order; perm_s = src in CSR order
__global__ void k_scatter(const int* __restrict__ src, const int* __restrict__ dst,
                          const int* __restrict__ off, int* __restrict__ cur,
                          int* __restrict__ rank, int* __restrict__ perm_s){
  int e = blockIdx.x * 256 + threadIdx.x;
  if (e >= NE) return;
  int d = dst[e];
  int pos = off[d] + atomicAdd(&cur[d], 1);
  rank[e] = pos;
  perm_s[pos] = src[e];
}

// ---------------- GEMM: C[M x Nc] = A[M x K] @ W[K x Nc] (+ bias) ----------------
// BM rows x 128 cols per block, 256 threads, (BM/16)x8 register micro-tile, BK=32.
// Register double-buffered staging: next tile's global loads fly under current compute.
template<int BM>
__global__ __launch_bounds__(256) void k_gemm_t(
    const float* __restrict__ A, const float* __restrict__ W,
    const float* __restrict__ bias, float* __restrict__ C,
    int M, int K, int Nc){
  constexpr int RM = BM / 16;     // rows per thread
  constexpr int AQ = BM / 32;     // float4 A-loads per thread
  __shared__ float As[32][BM + 4];   // [k][m], padded
  __shared__ float Ws[32][128];      // [k][n]
  int tid = threadIdx.x;
  int row0 = blockIdx.x * BM;
  int col0 = blockIdx.y * 128;
  int tr = (tid >> 4) & 15;
  int tc = tid & 15;
  int wk0 = tid >> 5;             // 0..7
  int wcc = (tid & 31) * 4;       // 0..124

  float4 pa[AQ], pw[4];
  #pragma unroll
  for (int q = 0; q < AQ; ++q) pa[q] = make_float4(0.f,0.f,0.f,0.f);

  float acc[RM][8];
  #pragma unroll
  for (int i = 0; i < RM; ++i)
    #pragma unroll
    for (int j = 0; j < 8; ++j) acc[i][j] = 0.f;

  // prologue loads (k0 = 0)
  #pragma unroll
  for (int q = 0; q < AQ; ++q){
    int idx = tid + q * 256;
    int gr = row0 + (idx >> 3);
    if (gr < M) pa[q] = *reinterpret_cast<const float4*>(A + (size_t)gr * K + ((idx & 7) * 4));
  }
  #pragma unroll
  for (int q = 0; q < 4; ++q)
    pw[q] = *reinterpret_cast<const float4*>(W + (size_t)(wk0 + q * 8) * Nc + col0 + wcc);

  for (int k0 = 0; k0 < K; k0 += 32){
    // stash current tile regs -> LDS
    #pragma unroll
    for (int q = 0; q < AQ; ++q){
      int idx = tid + q * 256;
      int r = idx >> 3, kk = (idx & 7) * 4;
      As[kk+0][r] = pa[q].x; As[kk+1][r] = pa[q].y;
      As[kk+2][r] = pa[q].z; As[kk+3][r] = pa[q].w;
    }
    #pragma unroll
    for (int q = 0; q < 4; ++q)
      *reinterpret_cast<float4*>(&Ws[wk0 + q * 8][wcc]) = pw[q];
    __syncthreads();
    // prefetch next tile
    if (k0 + 32 < K){
      int kn = k0 + 32;
      #pragma unroll
      for (int q = 0; q < AQ; ++q){
        int idx = tid + q * 256;
        int gr = row0 + (idx >> 3);
        pa[q] = make_float4(0.f,0.f,0.f,0.f);
        if (gr < M) pa[q] = *reinterpret_cast<const float4*>(A + (size_t)gr * K + kn + ((idx & 7) * 4));
      }
      #pragma unroll
      for (int q = 0; q < 4; ++q)
        pw[q] = *reinterpret_cast<const float4*>(W + (size_t)(kn + wk0 + q * 8) * Nc + col0 + wcc);
    }
    // compute current tile from LDS
    #pragma unroll 8
    for (int kk = 0; kk < 32; ++kk){
      float bv[8];
      float4 b0 = *reinterpret_cast<const float4*>(&Ws[kk][tc * 4]);
      float4 b1 = *reinterpret_cast<const float4*>(&Ws[kk][64 + tc * 4]);
      bv[0]=b0.x; bv[1]=b0.y; bv[2]=b0.z; bv[3]=b0.w;
      bv[4]=b1.x; bv[5]=b1.y; bv[6]=b1.z; bv[7]=b1.w;
      float av[RM];
      #pragma unroll
      for (int g = 0; g < RM / 4; ++g){
        float4 a = *reinterpret_cast<const float4*>(&As[kk][g * (BM >> 1) + tr * 4]);
        av[g*4+0]=a.x; av[g*4+1]=a.y; av[g*4+2]=a.z; av[g*4+3]=a.w;
      }
      #pragma unroll
      for (int i = 0; i < RM; ++i)
        #pragma unroll
        for (int j = 0; j < 8; ++j)
          acc[i][j] += av[i] * bv[j];
    }
    __syncthreads();
  }

  float4 bia0 = make_float4(0.f, 0.f, 0.f, 0.f), bia1 = bia0;
  if (bias){
    bia0 = *reinterpret_cast<const float4*>(bias + col0 + tc * 4);
    bia1 = *reinterpret_cast<const float4*>(bias + col0 + 64 + tc * 4);
  }
  #pragma unroll
  for (int i = 0; i < RM; ++i){
    int gr = row0 + (i >> 2) * (BM >> 1) + tr * 4 + (i & 3);
    if (gr < M){
      float4 v0 = make_float4(acc[i][0] + bia0.x, acc[i][1] + bia0.y,
                              acc[i][2] + bia0.z, acc[i][3] + bia0.w);
      float4 v1 = make_float4(acc[i][4] + bia1.x, acc[i][5] + bia1.y,
                              acc[i][6] + bia1.z, acc[i][7] + bia1.w);
      *reinterpret_cast<float4*>(C + (size_t)gr * Nc + col0 + tc * 4) = v0;
      *reinterpret_cast<float4*>(C + (size_t)gr * Nc + col0 + 64 + tc * 4) = v1;
    }
  }
}

// ---------------- Fused edge GEMM + edge_build (BM=128, Nc=128) ----------------
// ef_out = elu(lrelu(A@W + f_ni[src] + f_nj[dst] + bias)); logits in CSR order.
// Register double-buffered staging like k_gemm_t.
__global__ __launch_bounds__(256) void k_gemm_edge(
    const float* __restrict__ A, const float* __restrict__ W,
    const float* __restrict__ f_ni, const float* __restrict__ f_nj,
    const float* __restrict__ bias, const float* __restrict__ attn,
    const int* __restrict__ src, const int* __restrict__ dst,
    const int* __restrict__ rank,
    float* __restrict__ ef_out, float* __restrict__ logits_csr,
    int M, int K){
  __shared__ float As[32][132];
  __shared__ float Ws[32][128];
  int tid = threadIdx.x;
  int row0 = blockIdx.x * 128;
  int tr = (tid >> 4) & 15;
  int tc = tid & 15;
  int wk0 = tid >> 5;
  int wcc = (tid & 31) * 4;

  float4 pa[4], pw[4];
  #pragma unroll
  for (int q = 0; q < 4; ++q) pa[q] = make_float4(0.f,0.f,0.f,0.f);

  float acc[8][8];
  #pragma unroll
  for (int i = 0; i < 8; ++i)
    #pragma unroll
    for (int j = 0; j < 8; ++j) acc[i][j] = 0.f;

  #pragma unroll
  for (int q = 0; q < 4; ++q){
    int idx = tid + q * 256;
    int gr = row0 + (idx >> 3);
    if (gr < M) pa[q] = *reinterpret_cast<const float4*>(A + (size_t)gr * K + ((idx & 7) * 4));
  }
  #pragma unroll
  for (int q = 0; q < 4; ++q)
    pw[q] = *reinterpret_cast<const float4*>(W + (size_t)(wk0 + q * 8) * 128 + wcc);

  for (int k0 = 0; k0 < K; k0 += 32){
    #pragma unroll
    for (int q = 0; q < 4; ++q){
      int idx = tid + q * 256;
      int r = idx >> 3, kk = (idx & 7) * 4;
      As[kk+0][r] = pa[q].x; As[kk+1][r] = pa[q].y;
      As[kk+2][r] = pa[q].z; As[kk+3][r] = pa[q].w;
    }
    #pragma unroll
    for (int q = 0; q < 4; ++q)
      *reinterpret_cast<float4*>(&Ws[wk0 + q * 8][wcc]) = pw[q];
    __syncthreads();
    if (k0 + 32 < K){
      int kn = k0 + 32;
      #pragma unroll
      for (int q = 0; q < 4; ++q){
        int idx = tid + q * 256;
        int gr = row0 + (idx >> 3);
        pa[q] = make_float4(0.f,0.f,0.f,0.f);
        if (gr < M) pa[q] = *reinterpret_cast<const float4*>(A + (size_t)gr * K + kn + ((idx & 7) * 4));
      }
      #pragma unroll
      for (int q = 0; q < 4; ++q)
        pw[q] = *reinterpret_cast<const float4*>(W + (size_t)(kn + wk0 + q * 8) * 128 + wcc);
    }
    #pragma unroll 8
    for (int kk = 0; kk < 32; ++kk){
      float bv[8];
      float4 b0 = *reinterpret_cast<const float4*>(&Ws[kk][tc * 4]);
      float4 b1 = *reinterpret_cast<const float4*>(&Ws[kk][64 + tc * 4]);
      bv[0]=b0.x; bv[1]=b0.y; bv[2]=b0.z; bv[3]=b0.w;
      bv[4]=b1.x; bv[5]=b1.y; bv[6]=b1.z; bv[7]=b1.w;
      float av[8];
      float4 a0 = *reinterpret_cast<const float4*>(&As[kk][tr * 4]);
      float4 a1 = *reinterpret_cast<const float4*>(&As[kk][64 + tr * 4]);
      av[0]=a0.x; av[1]=a0.y; av[2]=a0.z; av[3]=a0.w;
      av[4]=a1.x; av[5]=a1.y; av[6]=a1.z; av[7]=a1.w;
      #pragma unroll
      for (int i = 0; i < 8; ++i)
        #pragma unroll
        for (int j = 0; j < 8; ++j)
          acc[i][j] += av[i] * bv[j];
    }
    __syncthreads();
  }

  // Epilogue: cols {tc*4+j} (head tc>>3) and {64+tc*4+j} (head 2+(tc>>3)).
  float4 at0 = *reinterpret_cast<const float4*>(attn + tc * 4);
  float4 at1 = *reinterpret_cast<const float4*>(attn + 64 + tc * 4);
  float4 bi0 = *reinterpret_cast<const float4*>(bias + tc * 4);
  float4 bi1 = *reinterpret_cast<const float4*>(bias + 64 + tc * 4);
  #pragma unroll
  for (int i = 0; i < 8; ++i){
    int gr = row0 + (i >> 2) * 64 + tr * 4 + (i & 3);   // uniform across the 16 tc-lanes
    if (gr >= M) continue;
    int sN = src[gr], dN = dst[gr];
    const float* ni = f_ni + (size_t)sN * 128;
    const float* nj = f_nj + (size_t)dN * 128;
    float4 n0 = *reinterpret_cast<const float4*>(ni + tc * 4);
    float4 n1 = *reinterpret_cast<const float4*>(ni + 64 + tc * 4);
    float4 m0 = *reinterpret_cast<const float4*>(nj + tc * 4);
    float4 m1 = *reinterpret_cast<const float4*>(nj + 64 + tc * 4);
    float v[8];
    v[0] = acc[i][0] + n0.x + m0.x + bi0.x;
    v[1] = acc[i][1] + n0.y + m0.y + bi0.y;
    v[2] = acc[i][2] + n0.z + m0.z + bi0.z;
    v[3] = acc[i][3] + n0.w + m0.w + bi0.w;
    v[4] = acc[i][4] + n1.x + m1.x + bi1.x;
    v[5] = acc[i][5] + n1.y + m1.y + bi1.y;
    v[6] = acc[i][6] + n1.z + m1.z + bi1.z;
    v[7] = acc[i][7] + n1.w + m1.w + bi1.w;
    #pragma unroll
    for (int j = 0; j < 8; ++j) v[j] = (v[j] >= 0.f) ? v[j] : 0.01f * v[j];
    float4 e0 = make_float4(v[0] > 0.f ? v[0] : expm1f(v[0]),
                            v[1] > 0.f ? v[1] : expm1f(v[1]),
                            v[2] > 0.f ? v[2] : expm1f(v[2]),
                            v[3] > 0.f ? v[3] : expm1f(v[3]));
    float4 e1 = make_float4(v[4] > 0.f ? v[4] : expm1f(v[4]),
                            v[5] > 0.f ? v[5] : expm1f(v[5]),
                            v[6] > 0.f ? v[6] : expm1f(v[6]),
                            v[7] > 0.f ? v[7] : expm1f(v[7]));
    *reinterpret_cast<float4*>(ef_out + (size_t)gr * 128 + tc * 4) = e0;
    *reinterpret_cast<float4*>(ef_out + (size_t)gr * 128 + 64 + tc * 4) = e1;
    float p0 = v[0]*at0.x + v[1]*at0.y + v[2]*at0.z + v[3]*at0.w;
    float p1 = v[4]*at1.x + v[5]*at1.y + v[6]*at1.z + v[7]*at1.w;
    p0 += __shfl_xor(p0, 1, 64); p0 += __shfl_xor(p0, 2, 64); p0 += __shfl_xor(p0, 4, 64);
    p1 += __shfl_xor(p1, 1, 64); p1 += __shfl_xor(p1, 2, 64); p1 += __shfl_xor(p1, 4, 64);
    float q0 = __shfl_xor(p0, 8, 64);   // other tc-half: head 1 / head 3
    float q1 = __shfl_xor(p1, 8, 64);
    if (tc == 0){
      int pos = rank[gr];
      *reinterpret_cast<float4*>(logits_csr + (size_t)pos * 4) =
          make_float4(p0, q0, p1, q1);  // heads 0,1,2,3
    }
  }
}

// One block per dst node: fused softmax + weighted aggregation + ELU. No atomics.
// 4-way unrolled gather loop: four independent h_src loads in flight per iter.
__global__ __launch_bounds__(256) void k_agg_csr(
    const int* __restrict__ off, const int* __restrict__ perm_s,
    const float* __restrict__ logits_csr, const float* __restrict__ h_src,
    float* __restrict__ out){
  int n = blockIdx.x;
  int c = threadIdx.x;
  int h = c >> 6;
  int beg = off[n], end = off[n + 1];
  float m = -INFINITY;
  for (int j = beg; j < end; ++j)
    m = fmaxf(m, logits_csr[(size_t)j * 4 + h]);
  float acc = 0.f, ssum = 0.f;
  int j = beg;
  for (; j + 4 <= end; j += 4){
    int s0 = perm_s[j], s1 = perm_s[j+1], s2 = perm_s[j+2], s3 = perm_s[j+3];
    float l0 = logits_csr[(size_t)j * 4 + h];
    float l1 = logits_csr[(size_t)(j+1) * 4 + h];
    float l2 = logits_csr[(size_t)(j+2) * 4 + h];
    float l3 = logits_csr[(size_t)(j+3) * 4 + h];
    float g0 = h_src[(size_t)s0 * 256 + c];
    float g1 = h_src[(size_t)s1 * 256 + c];
    float g2 = h_src[(size_t)s2 * 256 + c];
    float g3 = h_src[(size_t)s3 * 256 + c];
    float e0 = __expf(l0 - m), e1 = __expf(l1 - m);
    float e2 = __expf(l2 - m), e3 = __expf(l3 - m);
    ssum += (e0 + e1) + (e2 + e3);
    acc += e0 * g0 + e1 * g1 + e2 * g2 + e3 * g3;
  }
  for (; j < end; ++j){
    float ee = __expf(logits_csr[(size_t)j * 4 + h] - m);
    ssum += ee;
    acc += ee * h_src[(size_t)perm_s[j] * 256 + c];
  }
  float r = (end > beg) ? acc / ssum : 0.f;
  out[(size_t)n * 256 + c] = (r > 0.f) ? r : expm1f(r);
}

static void run_layer(const float* nf, int in_n, const float* ef, int in_e,
                      const float* Wsrc, const float* bsrc, const float* Wni,
                      const float* Wnj, const float* Wfij, const float* attn,
                      const float* bias, const int* src, const int* dst,
                      const int* off, const int* rank, const int* perm_s,
                      float* f_ni, float* f_nj, float* h_src, float* logits,
                      float* nf_out, float* ef_out, hipStream_t stream){
  dim3 gN((NN + 63) / 64, 1);
  dim3 gN2((NN + 63) / 64, 2);
  k_gemm_t<64><<<gN,  256, 0, stream>>>(nf, Wni, nullptr, f_ni, NN, in_n, 128);
  k_gemm_t<64><<<gN,  256, 0, stream>>>(nf, Wnj, nullptr, f_nj, NN, in_n, 128);
  k_gemm_t<64><<<gN2, 256, 0, stream>>>(nf, Wsrc, bsrc, h_src, NN, in_n, 256);
  k_gemm_edge<<<(NE + 127) / 128, 256, 0, stream>>>(
      ef, Wfij, f_ni, f_nj, bias, attn, src, dst, rank, ef_out, logits, NE, in_e);
  k_agg_csr<<<NN, 256, 0, stream>>>(off, perm_s, logits, h_src, nf_out);
}

extern "C" void kernel_launch(void* const* d_in, const int* in_sizes, int n_in,
                              void* d_out, int out_size, void* d_ws, size_t ws_size,
                              hipStream_t stream){
  const int*   node_types = (const int*)d_in[0];
  const int*   src        = (const int*)d_in[1];
  const int*   dst        = (const int*)d_in[2];
  const float* efeats     = (const float*)d_in[3];
  const float* table      = (const float*)d_in[4];
  const float* W_src0 = (const float*)d_in[5];
  const float* b_src0 = (const float*)d_in[6];
  const float* W_ni0  = (const float*)d_in[7];
  const float* W_nj0  = (const float*)d_in[8];
  const float* W_fij0 = (const float*)d_in[9];
  const float* attn0  = (const float*)d_in[10];
  const float* bias0  = (const float*)d_in[11];
  const float* W_src1 = (const float*)d_in[12];
  const float* b_src1 = (const float*)d_in[13];
  const float* W_ni1  = (const float*)d_in[14];
  const float* W_nj1  = (const float*)d_in[15];
  const float* W_fij1 = (const float*)d_in[16];
  const float* attn1  = (const float*)d_in[17];
  const float* bias1  = (const float*)d_in[18];

  char* w = (char*)d_ws;
  auto alloc = [&](size_t bytes){ void* p = (void*)w; w += (bytes + 255) & ~(size_t)255; return p; };
  float* nf_buf = (float*)alloc((size_t)NN * 256 * 4);
  float* f_ni   = (float*)alloc((size_t)NN * 128 * 4);
  float* f_nj   = (float*)alloc((size_t)NN * 128 * 4);
  float* h_src  = (float*)alloc((size_t)NN * 256 * 4);
  float* logits = (float*)alloc((size_t)NE * 4 * 4);
  int*   cnt    = (int*)  alloc((size_t)NN * 4);
  int*   cur    = (int*)  alloc((size_t)NN * 4);
  int*   off    = (int*)  alloc((size_t)(NN + 1) * 4);
  int*   rank   = (int*)  alloc((size_t)NE * 4);
  int*   perm_s = (int*)  alloc((size_t)NE * 4);

  float* out_nf = (float*)d_out;              // (NN, 256)
  float* out_ef = out_nf + (size_t)NN * 256;  // (NE, 128) — also doubles as ef1 staging

  // CSR (dst-grouped edge lists), built once, reused by both layers
  k_zero2<<<(NN + 255)/256, 256, 0, stream>>>(cnt, cur);
  k_hist<<<(NE + 255)/256, 256, 0, stream>>>(dst, cnt);
  k_scan<<<1, 1024, 0, stream>>>(cnt, off);
  k_scatter<<<(NE + 255)/256, 256, 0, stream>>>(src, dst, off, cur, rank, perm_s);

  // nf0 = embed_table[node_types]  (NN x 128)
  k_embed<<<(NN*128)/256, 256, 0, stream>>>(node_types, table, nf_buf);

  // Layer 0: in_n=128, in_e=64 -> nf1 (NN x 256) in nf_buf, ef1 (NE x 128) in out_ef
  run_layer(nf_buf, 128, efeats, 64,
            W_src0, b_src0, W_ni0, W_nj0, W_fij0, attn0, bias0,
            src, dst, off, rank, perm_s,
            f_ni, f_nj, h_src, logits, nf_buf, out_ef, stream);

  // Layer 1: in_n=256, in_e=128 -> outputs straight to d_out
  run_layer(nf_buf, 256, out_ef, 128,
            W_src1, b_src1, W_ni1, W_nj1, W_fij1, attn1, bias1,
            src, dst, off, rank, perm_s,
            f_ni, f_nj, h_src, logits, out_nf, out_ef, stream);
}

// Round 5
// 1417.131 us; speedup vs baseline: 1.1601x; 1.1601x over previous
//
#include <hip/hip_runtime.h>
#include <hip/hip_bf16.h>

#define NN 50000
#define NE 500000

__global__ void k_embed(const int* __restrict__ nt, const float* __restrict__ table,
                        float* __restrict__ nf){
  int i = blockIdx.x * 256 + threadIdx.x;   // i indexes float4s: NN*32
  if (i >= NN * 32) return;
  const float4* t4 = reinterpret_cast<const float4*>(table);
  reinterpret_cast<float4*>(nf)[i] = t4[nt[i >> 5] * 32 + (i & 31)];
}

// ---------------- CSR build (once per launch; reused by both layers) ----------------
__global__ void k_zero2(int* __restrict__ cnt, int* __restrict__ cur){
  int i = blockIdx.x * 256 + threadIdx.x;
  if (i < NN){ cnt[i] = 0; cur[i] = 0; }
}

__global__ void k_hist(const int* __restrict__ dst, int* __restrict__ cnt){
  int e = blockIdx.x * 256 + threadIdx.x;
  if (e < NE) atomicAdd(&cnt[dst[e]], 1);
}

// single-block exclusive scan over NN counts -> off[0..NN]
__global__ __launch_bounds__(1024) void k_scan(const int* __restrict__ cnt,
                                               int* __restrict__ off){
  __shared__ int ws[16];
  __shared__ int blocktot;
  __shared__ int carry_s;
  int tid = threadIdx.x;
  int lane = tid & 63, wv = tid >> 6;
  if (tid == 0) carry_s = 0;
  for (int base = 0; base < NN; base += 1024){
    int i = base + tid;
    int v = (i < NN) ? cnt[i] : 0;
    int x = v;
    #pragma unroll
    for (int d = 1; d < 64; d <<= 1){
      int t = __shfl_up(x, d, 64);
      if (lane >= d) x += t;
    }
    if (lane == 63) ws[wv] = x;
    __syncthreads();                    // also orders carry_s init
    if (tid == 0){
      int a = 0;
      #pragma unroll
      for (int k2 = 0; k2 < 16; ++k2){ int t = ws[k2]; ws[k2] = a; a += t; }
      blocktot = a;
    }
    __syncthreads();
    int carry = carry_s;
    if (i < NN) off[i] = carry + ws[wv] + (x - v);   // exclusive
    __syncthreads();
    if (tid == 0) carry_s = carry + blocktot;
    __syncthreads();
  }
  if (tid == 0) off[NN] = carry_s;
}

// rank[e] = position of edge e in dst-grouped (CSR) order; perm_s = src in CSR order
__global__ void k_scatter(const int* __restrict__ src, const int* __restrict__ dst,
                          const int* __restrict__ off, int* __restrict__ cur,
                          int* __restrict__ rank, int* __restrict__ perm_s){
  int e = blockIdx.x * 256 + threadIdx.x;
  if (e >= NE) return;
  int d = dst[e];
  int pos = off[d] + atomicAdd(&cur[d], 1);
  rank[e] = pos;
  perm_s[pos] = src[e];
}

// ---------------- GEMM: C[M x Nc] = A[M x K] @ W[K x Nc] (+ bias) ----------------
// BM rows x 128 cols per block, 256 threads, (BM/16)x8 register micro-tile, BK=32.
// Register double-buffered staging (kept for node GEMMs — small tiles, no L2 thrash).
template<int BM>
__global__ __launch_bounds__(256) void k_gemm_t(
    const float* __restrict__ A, const float* __restrict__ W,
    const float* __restrict__ bias, float* __restrict__ C,
    int M, int K, int Nc){
  constexpr int RM = BM / 16;     // rows per thread
  constexpr int AQ = BM / 32;     // float4 A-loads per thread
  __shared__ float As[32][BM + 4];   // [k][m], padded
  __shared__ float Ws[32][128];      // [k][n]
  int tid = threadIdx.x;
  int row0 = blockIdx.x * BM;
  int col0 = blockIdx.y * 128;
  int tr = (tid >> 4) & 15;
  int tc = tid & 15;
  int wk0 = tid >> 5;             // 0..7
  int wcc = (tid & 31) * 4;       // 0..124

  float4 pa[AQ], pw[4];
  #pragma unroll
  for (int q = 0; q < AQ; ++q) pa[q] = make_float4(0.f,0.f,0.f,0.f);

  float acc[RM][8];
  #pragma unroll
  for (int i = 0; i < RM; ++i)
    #pragma unroll
    for (int j = 0; j < 8; ++j) acc[i][j] = 0.f;

  // prologue loads (k0 = 0)
  #pragma unroll
  for (int q = 0; q < AQ; ++q){
    int idx = tid + q * 256;
    int gr = row0 + (idx >> 3);
    if (gr < M) pa[q] = *reinterpret_cast<const float4*>(A + (size_t)gr * K + ((idx & 7) * 4));
  }
  #pragma unroll
  for (int q = 0; q < 4; ++q)
    pw[q] = *reinterpret_cast<const float4*>(W + (size_t)(wk0 + q * 8) * Nc + col0 + wcc);

  for (int k0 = 0; k0 < K; k0 += 32){
    // stash current tile regs -> LDS
    #pragma unroll
    for (int q = 0; q < AQ; ++q){
      int idx = tid + q * 256;
      int r = idx >> 3, kk = (idx & 7) * 4;
      As[kk+0][r] = pa[q].x; As[kk+1][r] = pa[q].y;
      As[kk+2][r] = pa[q].z; As[kk+3][r] = pa[q].w;
    }
    #pragma unroll
    for (int q = 0; q < 4; ++q)
      *reinterpret_cast<float4*>(&Ws[wk0 + q * 8][wcc]) = pw[q];
    __syncthreads();
    // prefetch next tile
    if (k0 + 32 < K){
      int kn = k0 + 32;
      #pragma unroll
      for (int q = 0; q < AQ; ++q){
        int idx = tid + q * 256;
        int gr = row0 + (idx >> 3);
        pa[q] = make_float4(0.f,0.f,0.f,0.f);
        if (gr < M) pa[q] = *reinterpret_cast<const float4*>(A + (size_t)gr * K + kn + ((idx & 7) * 4));
      }
      #pragma unroll
      for (int q = 0; q < 4; ++q)
        pw[q] = *reinterpret_cast<const float4*>(W + (size_t)(kn + wk0 + q * 8) * Nc + col0 + wcc);
    }
    // compute current tile from LDS
    #pragma unroll 8
    for (int kk = 0; kk < 32; ++kk){
      float bv[8];
      float4 b0 = *reinterpret_cast<const float4*>(&Ws[kk][tc * 4]);
      float4 b1 = *reinterpret_cast<const float4*>(&Ws[kk][64 + tc * 4]);
      bv[0]=b0.x; bv[1]=b0.y; bv[2]=b0.z; bv[3]=b0.w;
      bv[4]=b1.x; bv[5]=b1.y; bv[6]=b1.z; bv[7]=b1.w;
      float av[RM];
      #pragma unroll
      for (int g = 0; g < RM / 4; ++g){
        float4 a = *reinterpret_cast<const float4*>(&As[kk][g * (BM >> 1) + tr * 4]);
        av[g*4+0]=a.x; av[g*4+1]=a.y; av[g*4+2]=a.z; av[g*4+3]=a.w;
      }
      #pragma unroll
      for (int i = 0; i < RM; ++i)
        #pragma unroll
        for (int j = 0; j < 8; ++j)
          acc[i][j] += av[i] * bv[j];
    }
    __syncthreads();
  }

  float4 bia0 = make_float4(0.f, 0.f, 0.f, 0.f), bia1 = bia0;
  if (bias){
    bia0 = *reinterpret_cast<const float4*>(bias + col0 + tc * 4);
    bia1 = *reinterpret_cast<const float4*>(bias + col0 + 64 + tc * 4);
  }
  #pragma unroll
  for (int i = 0; i < RM; ++i){
    int gr = row0 + (i >> 2) * (BM >> 1) + tr * 4 + (i & 3);
    if (gr < M){
      float4 v0 = make_float4(acc[i][0] + bia0.x, acc[i][1] + bia0.y,
                              acc[i][2] + bia0.z, acc[i][3] + bia0.w);
      float4 v1 = make_float4(acc[i][4] + bia1.x, acc[i][5] + bia1.y,
                              acc[i][6] + bia1.z, acc[i][7] + bia1.w);
      *reinterpret_cast<float4*>(C + (size_t)gr * Nc + col0 + tc * 4) = v0;
      *reinterpret_cast<float4*>(C + (size_t)gr * Nc + col0 + 64 + tc * 4) = v1;
    }
  }
}

// ---------------- Fused edge GEMM + edge_build (BM=128, Nc=128) ----------------
// REVERTED to single-buffered staging (round-2 structure): the register prefetch
// variant raised HBM bytes 652->918 MB (L2 store-line thrash) and cost +43 us.
__global__ __launch_bounds__(256) void k_gemm_edge(
    const float* __restrict__ A, const float* __restrict__ W,
    const float* __restrict__ f_ni, const float* __restrict__ f_nj,
    const float* __restrict__ bias, const float* __restrict__ attn,
    const int* __restrict__ src, const int* __restrict__ dst,
    const int* __restrict__ rank,
    float* __restrict__ ef_out, float* __restrict__ logits_csr,
    int M, int K){
  __shared__ float As[32][132];
  __shared__ float Ws[32][128];
  int tid = threadIdx.x;
  int row0 = blockIdx.x * 128;
  int tr = (tid >> 4) & 15;
  int tc = tid & 15;

  float acc[8][8];
  #pragma unroll
  for (int i = 0; i < 8; ++i)
    #pragma unroll
    for (int j = 0; j < 8; ++j) acc[i][j] = 0.f;

  for (int k0 = 0; k0 < K; k0 += 32){
    #pragma unroll
    for (int q = 0; q < 4; ++q){
      int idx = tid + q * 256;
      int r  = idx >> 3;
      int kk = (idx & 7) * 4;
      float4 v = make_float4(0.f, 0.f, 0.f, 0.f);
      int gr = row0 + r;
      if (gr < M) v = *reinterpret_cast<const float4*>(A + (size_t)gr * K + k0 + ((idx & 7) * 4));
      As[kk+0][r] = v.x; As[kk+1][r] = v.y; As[kk+2][r] = v.z; As[kk+3][r] = v.w;
    }
    #pragma unroll
    for (int q = 0; q < 4; ++q){
      int idx = tid + q * 256;
      int kk = idx >> 5;
      int cc = (idx & 31) * 4;
      *reinterpret_cast<float4*>(&Ws[kk][cc]) =
          *reinterpret_cast<const float4*>(W + (size_t)(k0 + kk) * 128 + cc);
    }
    __syncthreads();
    #pragma unroll 8
    for (int kk = 0; kk < 32; ++kk){
      float4 a0 = *reinterpret_cast<const float4*>(&As[kk][tr * 4]);
      float4 a1 = *reinterpret_cast<const float4*>(&As[kk][64 + tr * 4]);
      float4 b0 = *reinterpret_cast<const float4*>(&Ws[kk][tc * 4]);
      float4 b1 = *reinterpret_cast<const float4*>(&Ws[kk][64 + tc * 4]);
      float av[8] = {a0.x, a0.y, a0.z, a0.w, a1.x, a1.y, a1.z, a1.w};
      float bv[8] = {b0.x, b0.y, b0.z, b0.w, b1.x, b1.y, b1.z, b1.w};
      #pragma unroll
      for (int i = 0; i < 8; ++i)
        #pragma unroll
        for (int j = 0; j < 8; ++j)
          acc[i][j] += av[i] * bv[j];
    }
    __syncthreads();
  }

  // Epilogue: cols {tc*4+j} (head tc>>3) and {64+tc*4+j} (head 2+(tc>>3)).
  float4 at0 = *reinterpret_cast<const float4*>(attn + tc * 4);
  float4 at1 = *reinterpret_cast<const float4*>(attn + 64 + tc * 4);
  float4 bi0 = *reinterpret_cast<const float4*>(bias + tc * 4);
  float4 bi1 = *reinterpret_cast<const float4*>(bias + 64 + tc * 4);
  #pragma unroll
  for (int i = 0; i < 8; ++i){
    int gr = row0 + (i >> 2) * 64 + tr * 4 + (i & 3);   // uniform across the 16 tc-lanes
    if (gr >= M) continue;
    int sN = src[gr], dN = dst[gr];
    const float* ni = f_ni + (size_t)sN * 128;
    const float* nj = f_nj + (size_t)dN * 128;
    float4 n0 = *reinterpret_cast<const float4*>(ni + tc * 4);
    float4 n1 = *reinterpret_cast<const float4*>(ni + 64 + tc * 4);
    float4 m0 = *reinterpret_cast<const float4*>(nj + tc * 4);
    float4 m1 = *reinterpret_cast<const float4*>(nj + 64 + tc * 4);
    float v[8];
    v[0] = acc[i][0] + n0.x + m0.x + bi0.x;
    v[1] = acc[i][1] + n0.y + m0.y + bi0.y;
    v[2] = acc[i][2] + n0.z + m0.z + bi0.z;
    v[3] = acc[i][3] + n0.w + m0.w + bi0.w;
    v[4] = acc[i][4] + n1.x + m1.x + bi1.x;
    v[5] = acc[i][5] + n1.y + m1.y + bi1.y;
    v[6] = acc[i][6] + n1.z + m1.z + bi1.z;
    v[7] = acc[i][7] + n1.w + m1.w + bi1.w;
    #pragma unroll
    for (int j = 0; j < 8; ++j) v[j] = (v[j] >= 0.f) ? v[j] : 0.01f * v[j];
    float4 e0 = make_float4(v[0] > 0.f ? v[0] : expm1f(v[0]),
                            v[1] > 0.f ? v[1] : expm1f(v[1]),
                            v[2] > 0.f ? v[2] : expm1f(v[2]),
                            v[3] > 0.f ? v[3] : expm1f(v[3]));
    float4 e1 = make_float4(v[4] > 0.f ? v[4] : expm1f(v[4]),
                            v[5] > 0.f ? v[5] : expm1f(v[5]),
                            v[6] > 0.f ? v[6] : expm1f(v[6]),
                            v[7] > 0.f ? v[7] : expm1f(v[7]));
    *reinterpret_cast<float4*>(ef_out + (size_t)gr * 128 + tc * 4) = e0;
    *reinterpret_cast<float4*>(ef_out + (size_t)gr * 128 + 64 + tc * 4) = e1;
    float p0 = v[0]*at0.x + v[1]*at0.y + v[2]*at0.z + v[3]*at0.w;
    float p1 = v[4]*at1.x + v[5]*at1.y + v[6]*at1.z + v[7]*at1.w;
    p0 += __shfl_xor(p0, 1, 64); p0 += __shfl_xor(p0, 2, 64); p0 += __shfl_xor(p0, 4, 64);
    p1 += __shfl_xor(p1, 1, 64); p1 += __shfl_xor(p1, 2, 64); p1 += __shfl_xor(p1, 4, 64);
    float q0 = __shfl_xor(p0, 8, 64);   // other tc-half: head 1 / head 3
    float q1 = __shfl_xor(p1, 8, 64);
    if (tc == 0){
      int pos = rank[gr];
      *reinterpret_cast<float4*>(logits_csr + (size_t)pos * 4) =
          make_float4(p0, q0, p1, q1);  // heads 0,1,2,3
    }
  }
}

// Wave-per-node fused softmax + aggregation + ELU. 4 nodes per 256-thread block.
// Lane L handles cols [L*4, L*4+4) (head = L>>4); one float4 gather per edge per lane
// -> the wave covers the full 1 KB h_src row in one instruction. 4-way unrolled.
__global__ __launch_bounds__(256) void k_agg_csr(
    const int* __restrict__ off, const int* __restrict__ perm_s,
    const float* __restrict__ logits_csr, const float* __restrict__ h_src,
    float* __restrict__ out){
  int n = blockIdx.x * 4 + (threadIdx.x >> 6);
  if (n >= NN) return;
  int lane = threadIdx.x & 63;
  int h = lane >> 4;
  int beg = off[n], end = off[n + 1];
  float m = -INFINITY;
  for (int j = beg; j < end; ++j)
    m = fmaxf(m, logits_csr[(size_t)j * 4 + h]);
  float4 acc = make_float4(0.f, 0.f, 0.f, 0.f);
  float ssum = 0.f;
  int j = beg;
  for (; j + 4 <= end; j += 4){
    int s0 = perm_s[j], s1 = perm_s[j+1], s2 = perm_s[j+2], s3 = perm_s[j+3];
    float l0 = logits_csr[(size_t)j * 4 + h];
    float l1 = logits_csr[(size_t)(j+1) * 4 + h];
    float l2 = logits_csr[(size_t)(j+2) * 4 + h];
    float l3 = logits_csr[(size_t)(j+3) * 4 + h];
    float4 g0 = *reinterpret_cast<const float4*>(h_src + (size_t)s0 * 256 + lane * 4);
    float4 g1 = *reinterpret_cast<const float4*>(h_src + (size_t)s1 * 256 + lane * 4);
    float4 g2 = *reinterpret_cast<const float4*>(h_src + (size_t)s2 * 256 + lane * 4);
    float4 g3 = *reinterpret_cast<const float4*>(h_src + (size_t)s3 * 256 + lane * 4);
    float e0 = __expf(l0 - m), e1 = __expf(l1 - m);
    float e2 = __expf(l2 - m), e3 = __expf(l3 - m);
    ssum += (e0 + e1) + (e2 + e3);
    acc.x += e0*g0.x + e1*g1.x + e2*g2.x + e3*g3.x;
    acc.y += e0*g0.y + e1*g1.y + e2*g2.y + e3*g3.y;
    acc.z += e0*g0.z + e1*g1.z + e2*g2.z + e3*g3.z;
    acc.w += e0*g0.w + e1*g1.w + e2*g2.w + e3*g3.w;
  }
  for (; j < end; ++j){
    float ee = __expf(logits_csr[(size_t)j * 4 + h] - m);
    float4 g = *reinterpret_cast<const float4*>(h_src + (size_t)perm_s[j] * 256 + lane * 4);
    ssum += ee;
    acc.x += ee * g.x; acc.y += ee * g.y; acc.z += ee * g.z; acc.w += ee * g.w;
  }
  float inv = (end > beg) ? 1.f / ssum : 0.f;
  float r0 = acc.x * inv, r1 = acc.y * inv, r2 = acc.z * inv, r3 = acc.w * inv;
  float4 o = make_float4(r0 > 0.f ? r0 : expm1f(r0),
                         r1 > 0.f ? r1 : expm1f(r1),
                         r2 > 0.f ? r2 : expm1f(r2),
                         r3 > 0.f ? r3 : expm1f(r3));
  *reinterpret_cast<float4*>(out + (size_t)n * 256 + lane * 4) = o;
}

static void run_layer(const float* nf, int in_n, const float* ef, int in_e,
                      const float* Wsrc, const float* bsrc, const float* Wni,
                      const float* Wnj, const float* Wfij, const float* attn,
                      const float* bias, const int* src, const int* dst,
                      const int* off, const int* rank, const int* perm_s,
                      float* f_ni, float* f_nj, float* h_src, float* logits,
                      float* nf_out, float* ef_out, hipStream_t stream){
  dim3 gN((NN + 63) / 64, 1);
  dim3 gN2((NN + 63) / 64, 2);
  k_gemm_t<64><<<gN,  256, 0, stream>>>(nf, Wni, nullptr, f_ni, NN, in_n, 128);
  k_gemm_t<64><<<gN,  256, 0, stream>>>(nf, Wnj, nullptr, f_nj, NN, in_n, 128);
  k_gemm_t<64><<<gN2, 256, 0, stream>>>(nf, Wsrc, bsrc, h_src, NN, in_n, 256);
  k_gemm_edge<<<(NE + 127) / 128, 256, 0, stream>>>(
      ef, Wfij, f_ni, f_nj, bias, attn, src, dst, rank, ef_out, logits, NE, in_e);
  k_agg_csr<<<(NN + 3) / 4, 256, 0, stream>>>(off, perm_s, logits, h_src, nf_out);
}

extern "C" void kernel_launch(void* const* d_in, const int* in_sizes, int n_in,
                              void* d_out, int out_size, void* d_ws, size_t ws_size,
                              hipStream_t stream){
  const int*   node_types = (const int*)d_in[0];
  const int*   src        = (const int*)d_in[1];
  const int*   dst        = (const int*)d_in[2];
  const float* efeats     = (const float*)d_in[3];
  const float* table      = (const float*)d_in[4];
  const float* W_src0 = (const float*)d_in[5];
  const float* b_src0 = (const float*)d_in[6];
  const float* W_ni0  = (const float*)d_in[7];
  const float* W_nj0  = (const float*)d_in[8];
  const float* W_fij0 = (const float*)d_in[9];
  const float* attn0  = (const float*)d_in[10];
  const float* bias0  = (const float*)d_in[11];
  const float* W_src1 = (const float*)d_in[12];
  const float* b_src1 = (const float*)d_in[13];
  const float* W_ni1  = (const float*)d_in[14];
  const float* W_nj1  = (const float*)d_in[15];
  const float* W_fij1 = (const float*)d_in[16];
  const float* attn1  = (const float*)d_in[17];
  const float* bias1  = (const float*)d_in[18];

  char* w = (char*)d_ws;
  auto alloc = [&](size_t bytes){ void* p = (void*)w; w += (bytes + 255) & ~(size_t)255; return p; };
  float* nf_buf = (float*)alloc((size_t)NN * 256 * 4);
  float* f_ni   = (float*)alloc((size_t)NN * 128 * 4);
  float* f_nj   = (float*)alloc((size_t)NN * 128 * 4);
  float* h_src  = (float*)alloc((size_t)NN * 256 * 4);
  float* logits = (float*)alloc((size_t)NE * 4 * 4);
  int*   cnt    = (int*)  alloc((size_t)NN * 4);
  int*   cur    = (int*)  alloc((size_t)NN * 4);
  int*   off    = (int*)  alloc((size_t)(NN + 1) * 4);
  int*   rank   = (int*)  alloc((size_t)NE * 4);
  int*   perm_s = (int*)  alloc((size_t)NE * 4);

  float* out_nf = (float*)d_out;              // (NN, 256)
  float* out_ef = out_nf + (size_t)NN * 256;  // (NE, 128) — also doubles as ef1 staging

  // CSR (dst-grouped edge lists), built once, reused by both layers
  k_zero2<<<(NN + 255)/256, 256, 0, stream>>>(cnt, cur);
  k_hist<<<(NE + 255)/256, 256, 0, stream>>>(dst, cnt);
  k_scan<<<1, 1024, 0, stream>>>(cnt, off);
  k_scatter<<<(NE + 255)/256, 256, 0, stream>>>(src, dst, off, cur, rank, perm_s);

  // nf0 = embed_table[node_types]  (NN x 128)
  k_embed<<<(NN*32 + 255)/256, 256, 0, stream>>>(node_types, table, nf_buf);

  // Layer 0: in_n=128, in_e=64 -> nf1 (NN x 256) in nf_buf, ef1 (NE x 128) in out_ef
  run_layer(nf_buf, 128, efeats, 64,
            W_src0, b_src0, W_ni0, W_nj0, W_fij0, attn0, bias0,
            src, dst, off, rank, perm_s,
            f_ni, f_nj, h_src, logits, nf_buf, out_ef, stream);

  // Layer 1: in_n=256, in_e=128 -> outputs straight to d_out
  run_layer(nf_buf, 256, out_ef, 128,
            W_src1, b_src1, W_ni1, W_nj1, W_fij1, attn1, bias1,
            src, dst, off, rank, perm_s,
            f_ni, f_nj, h_src, logits, out_nf, out_ef, stream);
}